// Round 3
// baseline (4352.971 us; speedup 1.0000x reference)
//
#include <hip/hip_runtime.h>
#include <cstdint>
#include <cstddef>

#define T_OBS_C 64
#define T_UNOBS_C 32
#define BATCH_C 4096
#define HID_C 256
#define NSTEP 95

typedef short v8s __attribute__((ext_vector_type(8)));
typedef float v4f __attribute__((ext_vector_type(4)));

__device__ __forceinline__ float bf2f(unsigned short u) {
  union { unsigned int i; float f; } v; v.i = ((unsigned int)u) << 16; return v.f;
}
__device__ __forceinline__ unsigned short f2bf(float f) {
  union { float f; unsigned int i; } v; v.f = f;
  unsigned int r = (v.i + 0x7FFFu + ((v.i >> 16) & 1u)) >> 16;
  return (unsigned short)r;
}

// ---------------------------------------------------------------------------
// prep: Wc = wi @ stem_w2 (fp32 -> hi/lo bf16); wi, wh -> hi/lo bf16 splits;
//       bc_obs[n] = sum_j wi[n][j]*b2[j] + bi[n]
// ---------------------------------------------------------------------------
__global__ void prep_kernel(const float* __restrict__ wi,
                            const float* __restrict__ w2,
                            const float* __restrict__ b2,
                            const float* __restrict__ bi,
                            unsigned short* __restrict__ wi_hi,
                            unsigned short* __restrict__ wi_lo,
                            const float* __restrict__ wh,
                            unsigned short* __restrict__ wh_hi,
                            unsigned short* __restrict__ wh_lo,
                            unsigned short* __restrict__ wc_hi,
                            unsigned short* __restrict__ wc_lo,
                            float* __restrict__ bc_obs) {
  const int n = blockIdx.x;     // 0..767
  const int k = threadIdx.x;    // 0..255
  const int idx = n * 256 + k;

  float wv = wi[idx];
  unsigned short h1 = f2bf(wv);
  wi_hi[idx] = h1; wi_lo[idx] = f2bf(wv - bf2f(h1));

  float hv = wh[idx];
  unsigned short h2 = f2bf(hv);
  wh_hi[idx] = h2; wh_lo[idx] = f2bf(hv - bf2f(h2));

  float acc = 0.f;
  for (int j = 0; j < 256; ++j)
    acc += wi[n * 256 + j] * w2[j * 256 + k];
  unsigned short h3 = f2bf(acc);
  wc_hi[idx] = h3; wc_lo[idx] = f2bf(acc - bf2f(h3));

  if (k == 0) {
    float b = 0.f;
    for (int j = 0; j < 256; ++j) b += wi[n * 256 + j] * b2[j];
    bc_obs[n] = b + bi[n];
  }
}

// ---------------------------------------------------------------------------
// Persistent GRU kernel: all 95 steps in one launch. 512 WGs (2/CU, all
// co-resident). WG = 32 batch rows x 64 h-cols. The 4 col-siblings of a
// row-group handshake via a per-quartet device-scope flag each step; h is
// exchanged as packed (bf16 hi, bf16 lo) u32 via agent-scope atomics (L3),
// so per-XCD L2 stays warm with the weight matrices across all steps.
// ---------------------------------------------------------------------------
__global__ __launch_bounds__(256, 2)
void persist_kernel(const float* __restrict__ x_obs,
                    const float* __restrict__ t_obs,
                    const float* __restrict__ w1,
                    const float* __restrict__ b1,
                    const unsigned short* __restrict__ wi_hi,
                    const unsigned short* __restrict__ wi_lo,
                    const unsigned short* __restrict__ wh_hi,
                    const unsigned short* __restrict__ wh_lo,
                    const unsigned short* __restrict__ wc_hi,
                    const unsigned short* __restrict__ wc_lo,
                    const float* __restrict__ bc_obs,
                    const float* __restrict__ bi,
                    const float* __restrict__ bh,
                    unsigned int* __restrict__ hP0,
                    unsigned int* __restrict__ hP1,
                    int* __restrict__ flags,
                    float* __restrict__ out_z) {
  __shared__ __align__(16) unsigned short lds_h_hi[8192];
  __shared__ __align__(16) unsigned short lds_h_lo[8192];
  __shared__ __align__(16) unsigned short lds_x_hi[8192];
  __shared__ __align__(16) unsigned short lds_x_lo[8192];

  const int tid = threadIdx.x;
  const int wg = blockIdx.x;      // 0..511
  const int cg = wg & 3;          // col-group (64 h-cols)
  const int rg = wg >> 2;         // row-group (32 rows), 0..127
  const int m0 = rg * 32;
  const int j0 = cg * 64;

  const int wave = tid >> 6;
  const int lane = tid & 63;
  const int quad = lane >> 4;
  const int l16 = lane & 15;
  const int jw = j0 + wave * 16;
  const int jcol = jw + l16;

  // B-frag element offsets per gate (constant across steps)
  int bbase[3];
  #pragma unroll
  for (int g = 0; g < 3; ++g)
    bbase[g] = (g * 256 + jcol) * 256 + quad * 8;

  // stem thread mapping
  const int s_bl = tid >> 3;            // local row 0..31
  const int s_kb = (tid & 7) << 5;      // k-base, 8 threads x 32 cols

  for (int step = 0; step < NSTEP; ++step) {
    const bool is_obs = (step < 64);
    const int z_idx = (step == 63) ? 0 : (step >= 64 ? step - 63 : -1);

    // ---- phase 1: stem acts (obs only; independent of h, overlaps the wait)
    if (is_obs) {
      const int t = step;
      const int b = m0 + s_bl;
      const int xo = t * BATCH_C + b;
      float x0 = x_obs[(size_t)xo * 4 + 0];
      float x1 = x_obs[(size_t)xo * 4 + 1];
      float x2 = x_obs[(size_t)xo * 4 + 2];
      float x3 = x_obs[(size_t)xo * 4 + 3];
      float td = 0.f;
      if (t > 0) td = t_obs[xo] - t_obs[xo - BATCH_C];
      for (int j = 0; j < 32; ++j) {
        int k = s_kb + j;
        const float* wr = w1 + k * 5;
        float pre = x0 * wr[0] + x1 * wr[1] + x2 * wr[2] +
                    x3 * wr[3] + td * wr[4] + b1[k];
        float a = (pre > 0.f) ? pre : 0.01f * pre;
        unsigned short hi = f2bf(a);
        unsigned short lo = f2bf(a - bf2f(hi));
        int phys = (s_bl << 8) + ((((k >> 3) ^ (s_bl & 7))) << 3) + (k & 7);
        lds_x_hi[phys] = hi;
        lds_x_lo[phys] = lo;
      }
    }

    // ---- phase 2: wait for the quartet's previous-step h stores
    if (step > 0 && tid == 0) {
      int* f = flags + ((((step - 1) << 7) + rg) << 4);   // 64B-strided slots
      while (__hip_atomic_load(f, __ATOMIC_RELAXED, __HIP_MEMORY_SCOPE_AGENT) < 4)
        __builtin_amdgcn_s_sleep(8);
    }
    __syncthreads();

    // ---- phase 3: load h tile (32 rows x 256 cols) from L3, unpack to LDS
    const unsigned int* hcur = (step & 1) ? hP1 : hP0;
    unsigned int* hnext = (step & 1) ? hP0 : hP1;
    #pragma unroll
    for (int i = 0; i < 32; ++i) {
      unsigned int v = __hip_atomic_load(hcur + ((size_t)(m0 + i) << 8) + tid,
                                         __ATOMIC_RELAXED, __HIP_MEMORY_SCOPE_AGENT);
      int phys = (i << 8) + ((((tid >> 3) ^ (i & 7))) << 3) + (tid & 7);
      lds_h_hi[phys] = (unsigned short)(v >> 16);
      lds_h_lo[phys] = (unsigned short)(v & 0xffffu);
    }
    __syncthreads();

    // ---- phase 4: fused dual-GEMM (3-term bf16 hi/lo), merged r/z accs
    const unsigned short* Axh = is_obs ? lds_x_hi : lds_h_hi;
    const unsigned short* Axl = is_obs ? lds_x_lo : lds_h_lo;
    const unsigned short* BXh = is_obs ? wc_hi : wi_hi;
    const unsigned short* BXl = is_obs ? wc_lo : wi_lo;

    v4f aR[2], aZ[2], aNX[2], aNH[2];
    #pragma unroll
    for (int mt = 0; mt < 2; ++mt) {
      aR[mt] = (v4f){0.f,0.f,0.f,0.f};
      aZ[mt] = (v4f){0.f,0.f,0.f,0.f};
      aNX[mt] = (v4f){0.f,0.f,0.f,0.f};
      aNH[mt] = (v4f){0.f,0.f,0.f,0.f};
    }

    #pragma unroll
    for (int kc = 0; kc < 8; ++kc) {
      v8s bxh[3], bxl[3], bhh[3], bhl[3];
      #pragma unroll
      for (int g = 0; g < 3; ++g) {
        int bo = bbase[g] + kc * 32;
        bxh[g] = *(const v8s*)(BXh + bo);
        bxl[g] = *(const v8s*)(BXl + bo);
        bhh[g] = *(const v8s*)(wh_hi + bo);
        bhl[g] = *(const v8s*)(wh_lo + bo);
      }
      #pragma unroll
      for (int mt = 0; mt < 2; ++mt) {
        int arow = mt * 16 + l16;
        int chunk = (kc * 4 + quad) ^ (arow & 7);
        int aoff = (arow << 8) + (chunk << 3);
        v8s xh = *(const v8s*)(Axh + aoff);
        v8s xl = *(const v8s*)(Axl + aoff);
        v8s hh = *(const v8s*)(lds_h_hi + aoff);
        v8s hl = *(const v8s*)(lds_h_lo + aoff);
        // r gate: wi-part + wh-part into one acc
        aR[mt] = __builtin_amdgcn_mfma_f32_16x16x32_bf16(xh, bxh[0], aR[mt], 0,0,0);
        aR[mt] = __builtin_amdgcn_mfma_f32_16x16x32_bf16(xl, bxh[0], aR[mt], 0,0,0);
        aR[mt] = __builtin_amdgcn_mfma_f32_16x16x32_bf16(xh, bxl[0], aR[mt], 0,0,0);
        aR[mt] = __builtin_amdgcn_mfma_f32_16x16x32_bf16(hh, bhh[0], aR[mt], 0,0,0);
        aR[mt] = __builtin_amdgcn_mfma_f32_16x16x32_bf16(hl, bhh[0], aR[mt], 0,0,0);
        aR[mt] = __builtin_amdgcn_mfma_f32_16x16x32_bf16(hh, bhl[0], aR[mt], 0,0,0);
        // z gate
        aZ[mt] = __builtin_amdgcn_mfma_f32_16x16x32_bf16(xh, bxh[1], aZ[mt], 0,0,0);
        aZ[mt] = __builtin_amdgcn_mfma_f32_16x16x32_bf16(xl, bxh[1], aZ[mt], 0,0,0);
        aZ[mt] = __builtin_amdgcn_mfma_f32_16x16x32_bf16(xh, bxl[1], aZ[mt], 0,0,0);
        aZ[mt] = __builtin_amdgcn_mfma_f32_16x16x32_bf16(hh, bhh[1], aZ[mt], 0,0,0);
        aZ[mt] = __builtin_amdgcn_mfma_f32_16x16x32_bf16(hl, bhh[1], aZ[mt], 0,0,0);
        aZ[mt] = __builtin_amdgcn_mfma_f32_16x16x32_bf16(hh, bhl[1], aZ[mt], 0,0,0);
        // n gate: x-part and h-part kept separate (r gates h-part)
        aNX[mt] = __builtin_amdgcn_mfma_f32_16x16x32_bf16(xh, bxh[2], aNX[mt], 0,0,0);
        aNX[mt] = __builtin_amdgcn_mfma_f32_16x16x32_bf16(xl, bxh[2], aNX[mt], 0,0,0);
        aNX[mt] = __builtin_amdgcn_mfma_f32_16x16x32_bf16(xh, bxl[2], aNX[mt], 0,0,0);
        aNH[mt] = __builtin_amdgcn_mfma_f32_16x16x32_bf16(hh, bhh[2], aNH[mt], 0,0,0);
        aNH[mt] = __builtin_amdgcn_mfma_f32_16x16x32_bf16(hl, bhh[2], aNH[mt], 0,0,0);
        aNH[mt] = __builtin_amdgcn_mfma_f32_16x16x32_bf16(hh, bhl[2], aNH[mt], 0,0,0);
      }
    }

    // ---- phase 5: gate epilogue + h store (agent scope) + out_z
    const float* xb = is_obs ? bc_obs : bi;
    float xbr = xb[jcol], xbz = xb[256 + jcol], xbn = xb[512 + jcol];
    float hbr = bh[jcol], hbz = bh[256 + jcol], hbn = bh[512 + jcol];

    #pragma unroll
    for (int mt = 0; mt < 2; ++mt) {
      #pragma unroll
      for (int rgi = 0; rgi < 4; ++rgi) {
        int row_local = mt * 16 + quad * 4 + rgi;
        float gr = aR[mt][rgi] + xbr + hbr;
        float gz = aZ[mt][rgi] + xbz + hbz;
        float nx = aNX[mt][rgi] + xbn;
        float nh = aNH[mt][rgi] + hbn;
        float r = 1.f / (1.f + expf(-gr));
        float u = 1.f / (1.f + expf(-gz));
        float n = tanhf(nx + r * nh);
        int hp = (row_local << 8) + ((((jcol >> 3) ^ (row_local & 7))) << 3) + (jcol & 7);
        float hold = bf2f(lds_h_hi[hp]) + bf2f(lds_h_lo[hp]);
        float hnew = (1.f - u) * n + u * hold;
        unsigned short hi = f2bf(hnew);
        unsigned short lo = f2bf(hnew - bf2f(hi));
        unsigned int packed = ((unsigned int)hi << 16) | (unsigned int)lo;
        int gidx = ((m0 + row_local) << 8) + jcol;
        __hip_atomic_store(hnext + gidx, packed, __ATOMIC_RELAXED, __HIP_MEMORY_SCOPE_AGENT);
        if (z_idx >= 0) out_z[((size_t)z_idx << 20) + gidx] = hnew;
      }
    }

    // ---- phase 6: publish (barrier drains vmcnt; release orders the flag)
    __syncthreads();
    if (tid == 0)
      __hip_atomic_fetch_add(flags + (((step << 7) + rg) << 4), 1,
                             __ATOMIC_RELEASE, __HIP_MEMORY_SCOPE_AGENT);
  }
}

// ---------------------------------------------------------------------------
// head: x_hats = zs @ head_w.T + head_b.  8 threads/row, 8 independent
// float4 loads each -> latency-tolerant, HBM-bound (~20 us for 128 MB).
// ---------------------------------------------------------------------------
__global__ void head_kernel(const float* __restrict__ zs,
                            const float* __restrict__ head_w,
                            const float* __restrict__ head_b,
                            float* __restrict__ out_x) {
  const int g = blockIdx.x * 256 + threadIdx.x;
  const int row = g >> 3;
  const int sub = g & 7;                       // 32 k per sub-thread
  const float* zr = zs + ((size_t)row << 8) + sub * 32;
  float a0 = 0.f, a1 = 0.f, a2 = 0.f, a3 = 0.f;
  #pragma unroll
  for (int i = 0; i < 32; i += 4) {
    float4 z4 = *(const float4*)(zr + i);
    float zz[4] = {z4.x, z4.y, z4.z, z4.w};
    #pragma unroll
    for (int j = 0; j < 4; ++j) {
      int k = sub * 32 + i + j;
      a0 += zz[j] * head_w[k];
      a1 += zz[j] * head_w[256 + k];
      a2 += zz[j] * head_w[512 + k];
      a3 += zz[j] * head_w[768 + k];
    }
  }
  a0 += __shfl_xor(a0, 1); a0 += __shfl_xor(a0, 2); a0 += __shfl_xor(a0, 4);
  a1 += __shfl_xor(a1, 1); a1 += __shfl_xor(a1, 2); a1 += __shfl_xor(a1, 4);
  a2 += __shfl_xor(a2, 1); a2 += __shfl_xor(a2, 2); a2 += __shfl_xor(a2, 4);
  a3 += __shfl_xor(a3, 1); a3 += __shfl_xor(a3, 2); a3 += __shfl_xor(a3, 4);
  if (sub == 0) {
    size_t o = (size_t)row * 4;
    out_x[o + 0] = a0 + head_b[0];
    out_x[o + 1] = a1 + head_b[1];
    out_x[o + 2] = a2 + head_b[2];
    out_x[o + 3] = a3 + head_b[3];
  }
}

// ---------------------------------------------------------------------------
extern "C" void kernel_launch(void* const* d_in, const int* in_sizes, int n_in,
                              void* d_out, int out_size, void* d_ws, size_t ws_size,
                              hipStream_t stream) {
  const float* x_obs = (const float*)d_in[0];
  const float* t_obs = (const float*)d_in[1];
  const float* w1 = (const float*)d_in[3];
  const float* b1 = (const float*)d_in[4];
  const float* w2 = (const float*)d_in[5];
  const float* b2 = (const float*)d_in[6];
  const float* wi = (const float*)d_in[7];
  const float* wh = (const float*)d_in[8];
  const float* bi = (const float*)d_in[9];
  const float* bh = (const float*)d_in[10];
  const float* hw = (const float*)d_in[11];
  const float* hb = (const float*)d_in[12];

  float* out_x = (float*)d_out;                                  // [32,4096,4]
  float* out_z = out_x + (size_t)T_UNOBS_C * BATCH_C * 4;        // [32,4096,256]

  // workspace layout (bytes):
  //   [0,        4 MB)  hP0 (packed h, step-even input)        -- zeroed
  //   [4 MB,     5 MB)  quartet flags, 64B-strided             -- zeroed
  //   [5 MB,     9 MB)  hP1
  //   [9 MB,     ...)   weight splits (6 x 384 KB) + bc_obs
  char* ws = (char*)d_ws;
  unsigned int* hP0 = (unsigned int*)(ws);
  int* flags        = (int*)(ws + (4u << 20));
  unsigned int* hP1 = (unsigned int*)(ws + (5u << 20));
  unsigned short* wp = (unsigned short*)(ws + (9u << 20));
  unsigned short* wi_hi = wp; wp += 768 * 256;
  unsigned short* wi_lo = wp; wp += 768 * 256;
  unsigned short* wh_hi = wp; wp += 768 * 256;
  unsigned short* wh_lo = wp; wp += 768 * 256;
  unsigned short* wc_hi = wp; wp += 768 * 256;
  unsigned short* wc_lo = wp; wp += 768 * 256;
  float* bc_obs = (float*)wp;

  // zero h0 + flags (contiguous 5 MB)
  hipMemsetAsync(ws, 0, (size_t)5 << 20, stream);

  prep_kernel<<<768, 256, 0, stream>>>(wi, w2, b2, bi,
                                       wi_hi, wi_lo, wh, wh_hi, wh_lo,
                                       wc_hi, wc_lo, bc_obs);

  persist_kernel<<<512, 256, 0, stream>>>(x_obs, t_obs, w1, b1,
                                          wi_hi, wi_lo, wh_hi, wh_lo,
                                          wc_hi, wc_lo, bc_obs, bi, bh,
                                          hP0, hP1, flags, out_z);

  head_kernel<<<4096, 256, 0, stream>>>(out_z, hw, hb, out_x);
}

// Round 4
// 4223.228 us; speedup vs baseline: 1.0307x; 1.0307x over previous
//
#include <hip/hip_runtime.h>
#include <cstdint>
#include <cstddef>

#define T_OBS_C 64
#define T_UNOBS_C 32
#define BATCH_C 4096
#define HID_C 256
#define NSTEP 95

typedef short v8s __attribute__((ext_vector_type(8)));
typedef float v4f __attribute__((ext_vector_type(4)));
typedef unsigned short u16x8 __attribute__((ext_vector_type(8)));

__device__ __forceinline__ float bf2f(unsigned short u) {
  union { unsigned int i; float f; } v; v.i = ((unsigned int)u) << 16; return v.f;
}
__device__ __forceinline__ unsigned short f2bf(float f) {
  union { float f; unsigned int i; } v; v.f = f;
  unsigned int r = (v.i + 0x7FFFu + ((v.i >> 16) & 1u)) >> 16;
  return (unsigned short)r;
}

// Packed B-fragment offset for weight element (n, k), n in [0,768), k in [0,256):
// order [gate(3)][coltile(16)][kc(8)][quad(4)][l16(16)][j(8)] -> every wave
// B-load is a contiguous, coalesced 1KB dwordx4 burst.
__device__ __forceinline__ int pack_off(int n, int k) {
  int g = n >> 8, ctg = (n >> 4) & 15, l = n & 15;
  int kc = k >> 5, q = (k >> 3) & 3, j = k & 7;
  return ((((g * 16 + ctg) * 8 + kc) * 4 + q) * 128) + l * 8 + j;
}

// ---------------------------------------------------------------------------
// prep: Wc = wi @ stem_w2 (fp32); split wi/wh/wc into bf16 hi/lo, stored in
// packed MFMA-fragment order; bc_obs[n] = sum_j wi[n][j]*b2[j] + bi[n].
// ---------------------------------------------------------------------------
__global__ void prep_kernel(const float* __restrict__ wi,
                            const float* __restrict__ w2,
                            const float* __restrict__ b2,
                            const float* __restrict__ bi,
                            const float* __restrict__ wh,
                            unsigned short* __restrict__ wiP_hi,
                            unsigned short* __restrict__ wiP_lo,
                            unsigned short* __restrict__ whP_hi,
                            unsigned short* __restrict__ whP_lo,
                            unsigned short* __restrict__ wcP_hi,
                            unsigned short* __restrict__ wcP_lo,
                            float* __restrict__ bc_obs) {
  const int n = blockIdx.x;     // 0..767
  const int k = threadIdx.x;    // 0..255
  const int idx = n * 256 + k;
  const int po = pack_off(n, k);

  float wv = wi[idx];
  unsigned short h1 = f2bf(wv);
  wiP_hi[po] = h1; wiP_lo[po] = f2bf(wv - bf2f(h1));

  float hv = wh[idx];
  unsigned short h2 = f2bf(hv);
  whP_hi[po] = h2; whP_lo[po] = f2bf(hv - bf2f(h2));

  float acc = 0.f;
  for (int j = 0; j < 256; ++j)
    acc += wi[n * 256 + j] * w2[j * 256 + k];
  unsigned short h3 = f2bf(acc);
  wcP_hi[po] = h3; wcP_lo[po] = f2bf(acc - bf2f(h3));

  if (k == 0) {
    float b = 0.f;
    for (int j = 0; j < 256; ++j) b += wi[n * 256 + j] * b2[j];
    bc_obs[n] = b + bi[n];
  }
}

// ---------------------------------------------------------------------------
// Persistent GRU, batch-partitioned: 256 WGs x 512 threads (8 waves).
// WG owns 16 batch rows for all 95 steps; h ping-pongs entirely in LDS --
// NO inter-WG communication. Weights stream from L2 in packed frag order.
// Numerics identical to the passing round-2/3 kernels (3-term bf16 hi/lo).
// ---------------------------------------------------------------------------
__global__ __launch_bounds__(512, 2)
void persist_kernel(const float* __restrict__ x_obs,
                    const float* __restrict__ t_obs,
                    const float* __restrict__ w1,
                    const float* __restrict__ b1,
                    const unsigned short* __restrict__ wiP_hi,
                    const unsigned short* __restrict__ wiP_lo,
                    const unsigned short* __restrict__ whP_hi,
                    const unsigned short* __restrict__ whP_lo,
                    const unsigned short* __restrict__ wcP_hi,
                    const unsigned short* __restrict__ wcP_lo,
                    const float* __restrict__ bc_obs,
                    const float* __restrict__ bi,
                    const float* __restrict__ bh,
                    float* __restrict__ out_z) {
  // h layout: elem (row r<16, col k<256) at phys (r<<8) + (((k>>3)^(r&7))<<3) + (k&7)
  __shared__ __align__(16) unsigned short sh_h_hi[2][4096];   // 16 KB
  __shared__ __align__(16) unsigned short sh_h_lo[2][4096];   // 16 KB
  __shared__ __align__(16) unsigned short sh_x_hi[4096];      // 8 KB
  __shared__ __align__(16) unsigned short sh_x_lo[4096];      // 8 KB

  const int tid = threadIdx.x;
  const int m0 = blockIdx.x * 16;       // this WG's batch rows

  const int wv = tid >> 6;              // wave 0..7 -> cols [wv*32, wv*32+32)
  const int lane = tid & 63;
  const int quad = lane >> 4;
  const int l16 = lane & 15;

  // packed B-frag base offsets (elements) per [coltile][gate]
  int boff[2][3];
  #pragma unroll
  for (int ct = 0; ct < 2; ++ct)
    #pragma unroll
    for (int g = 0; g < 3; ++g)
      boff[ct][g] = ((((g * 16 + wv * 2 + ct) * 8) * 4 + quad) * 128) + l16 * 8;

  // stem mapping: thread -> (row, 8 consecutive k)
  const int s_r = tid >> 5;             // 0..15
  const int s_kb = (tid & 31) << 3;     // 0,8,..,248

  // init h0 = 0 in buffer 0
  *(u16x8*)(sh_h_hi[0] + tid * 8) = (u16x8)0;
  *(u16x8*)(sh_h_lo[0] + tid * 8) = (u16x8)0;

  for (int step = 0; step < NSTEP; ++step) {
    const bool is_obs = (step < T_OBS_C);
    const int z_idx = (step == 63) ? 0 : (step >= 64 ? step - 63 : -1);
    const unsigned short* hc_hi = sh_h_hi[step & 1];
    const unsigned short* hc_lo = sh_h_lo[step & 1];
    unsigned short* hn_hi = sh_h_hi[(step & 1) ^ 1];
    unsigned short* hn_lo = sh_h_lo[(step & 1) ^ 1];

    // [A] prev epilogue h-writes + prev GEMM x-reads complete
    __syncthreads();

    if (is_obs) {
      const int t = step;
      const int xo = t * BATCH_C + (m0 + s_r);
      float x0 = x_obs[(size_t)xo * 4 + 0];
      float x1 = x_obs[(size_t)xo * 4 + 1];
      float x2 = x_obs[(size_t)xo * 4 + 2];
      float x3 = x_obs[(size_t)xo * 4 + 3];
      float td = (t > 0) ? (t_obs[xo] - t_obs[xo - BATCH_C]) : 0.f;
      u16x8 vhi, vlo;
      #pragma unroll
      for (int j = 0; j < 8; ++j) {
        int k = s_kb + j;
        const float* wr = w1 + k * 5;
        float pre = x0 * wr[0] + x1 * wr[1] + x2 * wr[2] +
                    x3 * wr[3] + td * wr[4] + b1[k];
        float a = (pre > 0.f) ? pre : 0.01f * pre;
        unsigned short hi = f2bf(a);
        vhi[j] = hi;
        vlo[j] = f2bf(a - bf2f(hi));
      }
      int base = (s_r << 8) + ((((s_kb >> 3) ^ (s_r & 7))) << 3);
      *(u16x8*)(sh_x_hi + base) = vhi;
      *(u16x8*)(sh_x_lo + base) = vlo;
      __syncthreads();   // [B] stem visible to GEMM
    }

    const unsigned short* BXh = is_obs ? wcP_hi : wiP_hi;
    const unsigned short* BXl = is_obs ? wcP_lo : wiP_lo;

    v4f aR[2], aZ[2], aNX[2], aNH[2];
    #pragma unroll
    for (int ct = 0; ct < 2; ++ct) {
      aR[ct] = (v4f){0.f,0.f,0.f,0.f};
      aZ[ct] = (v4f){0.f,0.f,0.f,0.f};
      aNX[ct] = (v4f){0.f,0.f,0.f,0.f};
      aNH[ct] = (v4f){0.f,0.f,0.f,0.f};
    }

    #pragma unroll
    for (int kc = 0; kc < 8; ++kc) {
      int chunk = ((kc << 2) + quad) ^ (l16 & 7);
      int aoff = (l16 << 8) + (chunk << 3);
      v8s hh = *(const v8s*)(hc_hi + aoff);
      v8s hl = *(const v8s*)(hc_lo + aoff);
      v8s xh, xl;
      if (is_obs) {
        xh = *(const v8s*)(sh_x_hi + aoff);
        xl = *(const v8s*)(sh_x_lo + aoff);
      } else { xh = hh; xl = hl; }

      #pragma unroll
      for (int ct = 0; ct < 2; ++ct) {
        v8s bxh[3], bxl[3], bhh[3], bhl[3];
        #pragma unroll
        for (int g = 0; g < 3; ++g) {
          int bo = boff[ct][g] + kc * 512;
          bxh[g] = *(const v8s*)(BXh + bo);
          bxl[g] = *(const v8s*)(BXl + bo);
          bhh[g] = *(const v8s*)(whP_hi + bo);
          bhl[g] = *(const v8s*)(whP_lo + bo);
        }
        aR[ct] = __builtin_amdgcn_mfma_f32_16x16x32_bf16(xh, bxh[0], aR[ct], 0,0,0);
        aR[ct] = __builtin_amdgcn_mfma_f32_16x16x32_bf16(xl, bxh[0], aR[ct], 0,0,0);
        aR[ct] = __builtin_amdgcn_mfma_f32_16x16x32_bf16(xh, bxl[0], aR[ct], 0,0,0);
        aR[ct] = __builtin_amdgcn_mfma_f32_16x16x32_bf16(hh, bhh[0], aR[ct], 0,0,0);
        aR[ct] = __builtin_amdgcn_mfma_f32_16x16x32_bf16(hl, bhh[0], aR[ct], 0,0,0);
        aR[ct] = __builtin_amdgcn_mfma_f32_16x16x32_bf16(hh, bhl[0], aR[ct], 0,0,0);

        aZ[ct] = __builtin_amdgcn_mfma_f32_16x16x32_bf16(xh, bxh[1], aZ[ct], 0,0,0);
        aZ[ct] = __builtin_amdgcn_mfma_f32_16x16x32_bf16(xl, bxh[1], aZ[ct], 0,0,0);
        aZ[ct] = __builtin_amdgcn_mfma_f32_16x16x32_bf16(xh, bxl[1], aZ[ct], 0,0,0);
        aZ[ct] = __builtin_amdgcn_mfma_f32_16x16x32_bf16(hh, bhh[1], aZ[ct], 0,0,0);
        aZ[ct] = __builtin_amdgcn_mfma_f32_16x16x32_bf16(hl, bhh[1], aZ[ct], 0,0,0);
        aZ[ct] = __builtin_amdgcn_mfma_f32_16x16x32_bf16(hh, bhl[1], aZ[ct], 0,0,0);

        aNX[ct] = __builtin_amdgcn_mfma_f32_16x16x32_bf16(xh, bxh[2], aNX[ct], 0,0,0);
        aNX[ct] = __builtin_amdgcn_mfma_f32_16x16x32_bf16(xl, bxh[2], aNX[ct], 0,0,0);
        aNX[ct] = __builtin_amdgcn_mfma_f32_16x16x32_bf16(xh, bxl[2], aNX[ct], 0,0,0);
        aNH[ct] = __builtin_amdgcn_mfma_f32_16x16x32_bf16(hh, bhh[2], aNH[ct], 0,0,0);
        aNH[ct] = __builtin_amdgcn_mfma_f32_16x16x32_bf16(hl, bhh[2], aNH[ct], 0,0,0);
        aNH[ct] = __builtin_amdgcn_mfma_f32_16x16x32_bf16(hh, bhl[2], aNH[ct], 0,0,0);
      }
    }

    // epilogue: lane owns (rows quad*4..+3) x (col jcol) per coltile
    const float* xb = is_obs ? bc_obs : bi;
    #pragma unroll
    for (int ct = 0; ct < 2; ++ct) {
      const int jcol = wv * 32 + ct * 16 + l16;
      float xbr = xb[jcol], xbz = xb[256 + jcol], xbn = xb[512 + jcol];
      float hbr = bh[jcol], hbz = bh[256 + jcol], hbn = bh[512 + jcol];
      #pragma unroll
      for (int rg = 0; rg < 4; ++rg) {
        int row = quad * 4 + rg;
        float gr = aR[ct][rg] + xbr + hbr;
        float gz = aZ[ct][rg] + xbz + hbz;
        float nx = aNX[ct][rg] + xbn;
        float nh = aNH[ct][rg] + hbn;
        float r = 1.f / (1.f + expf(-gr));
        float u = 1.f / (1.f + expf(-gz));
        float n = tanhf(nx + r * nh);
        int hp = (row << 8) + ((((jcol >> 3) ^ (row & 7))) << 3) + (jcol & 7);
        float hold = bf2f(hc_hi[hp]) + bf2f(hc_lo[hp]);
        float hnew = (1.f - u) * n + u * hold;
        unsigned short hi = f2bf(hnew);
        hn_hi[hp] = hi;
        hn_lo[hp] = f2bf(hnew - bf2f(hi));
        if (z_idx >= 0)
          out_z[((size_t)z_idx << 20) + ((size_t)(m0 + row) << 8) + jcol] = hnew;
      }
    }
  }
}

// ---------------------------------------------------------------------------
// head: x_hats = zs @ head_w.T + head_b
// ---------------------------------------------------------------------------
__global__ void head_kernel(const float* __restrict__ zs,
                            const float* __restrict__ head_w,
                            const float* __restrict__ head_b,
                            float* __restrict__ out_x) {
  const int g = blockIdx.x * 256 + threadIdx.x;
  const int row = g >> 3;
  const int sub = g & 7;
  const float* zr = zs + ((size_t)row << 8) + sub * 32;
  float a0 = 0.f, a1 = 0.f, a2 = 0.f, a3 = 0.f;
  #pragma unroll
  for (int i = 0; i < 32; i += 4) {
    float4 z4 = *(const float4*)(zr + i);
    float zz[4] = {z4.x, z4.y, z4.z, z4.w};
    #pragma unroll
    for (int j = 0; j < 4; ++j) {
      int k = sub * 32 + i + j;
      a0 += zz[j] * head_w[k];
      a1 += zz[j] * head_w[256 + k];
      a2 += zz[j] * head_w[512 + k];
      a3 += zz[j] * head_w[768 + k];
    }
  }
  a0 += __shfl_xor(a0, 1); a0 += __shfl_xor(a0, 2); a0 += __shfl_xor(a0, 4);
  a1 += __shfl_xor(a1, 1); a1 += __shfl_xor(a1, 2); a1 += __shfl_xor(a1, 4);
  a2 += __shfl_xor(a2, 1); a2 += __shfl_xor(a2, 2); a2 += __shfl_xor(a2, 4);
  a3 += __shfl_xor(a3, 1); a3 += __shfl_xor(a3, 2); a3 += __shfl_xor(a3, 4);
  if (sub == 0) {
    size_t o = (size_t)row * 4;
    out_x[o + 0] = a0 + head_b[0];
    out_x[o + 1] = a1 + head_b[1];
    out_x[o + 2] = a2 + head_b[2];
    out_x[o + 3] = a3 + head_b[3];
  }
}

// ---------------------------------------------------------------------------
extern "C" void kernel_launch(void* const* d_in, const int* in_sizes, int n_in,
                              void* d_out, int out_size, void* d_ws, size_t ws_size,
                              hipStream_t stream) {
  const float* x_obs = (const float*)d_in[0];
  const float* t_obs = (const float*)d_in[1];
  const float* w1 = (const float*)d_in[3];
  const float* b1 = (const float*)d_in[4];
  const float* w2 = (const float*)d_in[5];
  const float* b2 = (const float*)d_in[6];
  const float* wi = (const float*)d_in[7];
  const float* wh = (const float*)d_in[8];
  const float* bi = (const float*)d_in[9];
  const float* bh = (const float*)d_in[10];
  const float* hw = (const float*)d_in[11];
  const float* hb = (const float*)d_in[12];

  float* out_x = (float*)d_out;                                  // [32,4096,4]
  float* out_z = out_x + (size_t)T_UNOBS_C * BATCH_C * 4;        // [32,4096,256]

  // workspace: 6 packed weight splits (384 KB each) + bc_obs
  unsigned short* wp = (unsigned short*)d_ws;
  unsigned short* wiP_hi = wp; wp += 768 * 256;
  unsigned short* wiP_lo = wp; wp += 768 * 256;
  unsigned short* whP_hi = wp; wp += 768 * 256;
  unsigned short* whP_lo = wp; wp += 768 * 256;
  unsigned short* wcP_hi = wp; wp += 768 * 256;
  unsigned short* wcP_lo = wp; wp += 768 * 256;
  float* bc_obs = (float*)wp;

  prep_kernel<<<768, 256, 0, stream>>>(wi, w2, b2, bi, wh,
                                       wiP_hi, wiP_lo, whP_hi, whP_lo,
                                       wcP_hi, wcP_lo, bc_obs);

  persist_kernel<<<256, 512, 0, stream>>>(x_obs, t_obs, w1, b1,
                                          wiP_hi, wiP_lo, whP_hi, whP_lo,
                                          wcP_hi, wcP_lo, bc_obs, bi, bh,
                                          out_z);

  head_kernel<<<4096, 256, 0, stream>>>(out_z, hw, hb, out_x);
}